// Round 4
// baseline (79.632 us; speedup 1.0000x reference)
//
#include <hip/hip_runtime.h>

// RBF-MMD discriminator: B=512 rows, T=128 slabs, C=16, fp32.
// out = E_xx - 2*E_xy over per-slab RBF grams (slab weight 1 for t in {0,127},
// else 2; 254 weighted slab instances).
//
// R4 structure: the slab access pattern (rows 2 KB apart -> 1 cache line per
// row) made every gram block do ~600 scattered 64B transactions; that request
// rate, not the main loop, was the ~30 us cost. prep_kernel now does the
// scatter ONCE (8 MB, fully-used lines), fusing the split-bf16 conversion and
// norm/scale math, and writes slab-major arrays to d_ws. gram_kernel reads
// everything coalesced and keeps the R3 main loop (verified, absmax 9.5e-7).
//
// Split-bf16 MFMA (verified 16x16x32_bf16 layouts):
//   S = A1*B1 + A2*B2, A1=[ahi|alo] B1=[bhi|bhi], A2=[ahi|0] B2=[blo|blo]
//   (lo*lo dropped: ~2^-18 relative, zero-mean).
// Inputs pre-scaled by sqrt(log2 e); entry = exp2(dot') * 2^-gcol * 2^-grow,
// accumulated as fma(exp2(dot'), colscale, acc); row-scale in epilogue.

#define LOG2E 1.4426950408889634f
#define SCALE 1.2011224087864498f   // sqrt(LOG2E)

// d_ws layout (dword offsets). [t][row][8dw] for H/L arrays, [t*512+row] scalars.
#define XH_OFF   0u
#define XL_OFF   524288u
#define YH_OFF   1048576u
#define YL_OFF   1572864u
#define GX_OFF   2097152u   // g = 0.5*log2e*|x_row|^2 (A-row scales, fp32)
#define CSX_OFF  2162688u   // 2^-g for x (column scales)
#define CSY_OFF  2228224u   // 2^-g for y
#define PART_OFF 2293760u   // 2048 floats of block partials

typedef __attribute__((ext_vector_type(8))) __bf16 bf16x8;
typedef __attribute__((ext_vector_type(4))) float floatx4;

union FragU { uint4 q; unsigned int u[4]; bf16x8 v; };

// 16B-aligned group-padded LDS row offset (dwords): 8 dw/row + 4 dw pad per 4
// rows -> b128 frag reads are 2-way bank aliased (free per m136).
static __device__ __forceinline__ int off(int n) { return (n << 3) + ((n >> 2) << 2); }

static __device__ __forceinline__ unsigned short bfbits(__bf16 h) {
    union { __bf16 h; unsigned short s; } u; u.h = h; return u.s;
}
static __device__ __forceinline__ unsigned int packhh(__bf16 a, __bf16 b) {
    return (unsigned int)bfbits(a) | ((unsigned int)bfbits(b) << 16);
}

// grid 512: bid>>8 = matrix (0=x,1=y), (bid>>1)&127 = t, bid&1 = row-half.
// Thread handles one (t,row): reads its 64B line (scattered, fully used),
// writes H/L (32B each) and scales COALESCED (consecutive tid = consecutive row).
__global__ __launch_bounds__(256) void prep_kernel(const float* __restrict__ x,
                                                   const float* __restrict__ y,
                                                   unsigned int* __restrict__ ws) {
    const int bid = blockIdx.x, tid = threadIdx.x;
    const int m   = bid >> 8;
    const int t   = (bid >> 1) & 127;
    const int row = ((bid & 1) << 8) + tid;

    const float4* __restrict__ src4 = m ? (const float4*)y : (const float4*)x;
    const size_t gb = (size_t)row * 512 + t * 4;
    float4 f0 = src4[gb], f1 = src4[gb + 1], f2 = src4[gb + 2], f3 = src4[gb + 3];
    const float fs[16] = { f0.x, f0.y, f0.z, f0.w, f1.x, f1.y, f1.z, f1.w,
                           f2.x, f2.y, f2.z, f2.w, f3.x, f3.y, f3.z, f3.w };
    float g = 0.f;
    unsigned int hw[8], lw[8];
#pragma unroll
    for (int p = 0; p < 8; ++p) {
        const float v0 = fs[2 * p], v1 = fs[2 * p + 1];
        g += v0 * v0 + v1 * v1;
        const float s0 = v0 * SCALE, s1 = v1 * SCALE;
        const __bf16 h0 = (__bf16)s0, h1 = (__bf16)s1;
        hw[p] = packhh(h0, h1);
        lw[p] = packhh((__bf16)(s0 - (float)h0), (__bf16)(s1 - (float)h1));
    }
    const float gp = 0.5f * LOG2E * g;
    const unsigned int idx = (unsigned int)t * 512u + (unsigned int)row;
    unsigned int* __restrict__ H = ws + (m ? YH_OFF : XH_OFF) + (size_t)idx * 8;
    unsigned int* __restrict__ L = ws + (m ? YL_OFF : XL_OFF) + (size_t)idx * 8;
    *(uint4*)&H[0] = make_uint4(hw[0], hw[1], hw[2], hw[3]);
    *(uint4*)&H[4] = make_uint4(hw[4], hw[5], hw[6], hw[7]);
    *(uint4*)&L[0] = make_uint4(lw[0], lw[1], lw[2], lw[3]);
    *(uint4*)&L[4] = make_uint4(lw[4], lw[5], lw[6], lw[7]);
    float* __restrict__ wsf = (float*)ws;
    wsf[(m ? CSY_OFF : CSX_OFF) + idx] = __builtin_amdgcn_exp2f(-gp);
    if (!m) wsf[GX_OFF + idx] = gp;
}

// grid 1024: bid>>3 = t, (bid>>2)&1 = A-strip (256 rows), bid&3 = j-quarter
// (128 cols). 4 waves; wave w owns A rows strip*256 + w*64 (four 16-row tiles).
__global__ __launch_bounds__(256, 4) void gram_kernel(const unsigned int* __restrict__ ws,
                                                      float* __restrict__ part) {
    __shared__ unsigned int XHs[1152], XLs[1152], YHs[1152], YLs[1152];
    __shared__ float csx[128], csy[128];   // 2^-g per j-column
    __shared__ float srg[256];             // g per A-row (local to strip)
    __shared__ float red[8];

    const int bid   = blockIdx.x;
    const int t     = bid >> 3;
    const int strip = (bid >> 2) & 1;
    const int jq    = bid & 3;
    const int tid   = threadIdx.x;
    const int w     = tid >> 6;
    const int lane  = tid & 63;
    const int quad  = lane >> 4;
    const int l15   = lane & 15;
    const int qh    = quad & 1;
    const float* __restrict__ wsf = (const float*)ws;

    // ---- coalesced staging: wave a loads one 4KB array strip (128 rows) ----
    {
        const int a = tid >> 6, idx = tid & 63;
        const unsigned int abase = (a == 0) ? XH_OFF : (a == 1) ? XL_OFF
                                 : (a == 2) ? YH_OFF : YL_OFF;
        const unsigned int* __restrict__ gsrc =
            ws + abase + ((size_t)t * 512 + jq * 128) * 8 + (size_t)idx * 16;
        uint4 q0 = *(const uint4*)&gsrc[0];
        uint4 q1 = *(const uint4*)&gsrc[4];
        uint4 q2 = *(const uint4*)&gsrc[8];
        uint4 q3 = *(const uint4*)&gsrc[12];
        unsigned int* __restrict__ dst = (a == 0) ? XHs : (a == 1) ? XLs
                                       : (a == 2) ? YHs : YLs;
        const int r0 = idx * 2;
        *(uint4*)&dst[off(r0)]         = q0;
        *(uint4*)&dst[off(r0) + 4]     = q1;
        *(uint4*)&dst[off(r0 + 1)]     = q2;
        *(uint4*)&dst[off(r0 + 1) + 4] = q3;
    }
    // column scales (coalesced)
    if (tid < 128) csx[tid]       = wsf[CSX_OFF + t * 512 + jq * 128 + tid];
    else           csy[tid - 128] = wsf[CSY_OFF + t * 512 + jq * 128 + (tid - 128)];
    // A-row g's (coalesced)
    srg[tid] = wsf[GX_OFF + t * 512 + strip * 256 + tid];

    // ---- A fragments: direct coalesced uint4 loads of precomputed H/L ----
    bf16x8 a1f[4], a2f[4];
    {
        FragU z; z.q = make_uint4(0u, 0u, 0u, 0u);
        const unsigned int hbase = (quad < 2) ? XH_OFF : XL_OFF;
#pragma unroll
        for (int rt = 0; rt < 4; ++rt) {
            const int row = strip * 256 + w * 64 + rt * 16 + l15;
            const unsigned int* __restrict__ p =
                ws + hbase + ((size_t)t * 512 + row) * 8 + qh * 4;
            FragU u; u.q = *(const uint4*)p;
            a1f[rt] = u.v;                       // A1 = [ahi | alo]
            a2f[rt] = (quad < 2) ? u.v : z.v;    // A2 = [ahi |  0 ]
        }
    }
    __syncthreads();

    float sxx[4][4], sxy[4][4];
#pragma unroll
    for (int rt = 0; rt < 4; ++rt)
#pragma unroll
        for (int r = 0; r < 4; ++r) { sxx[rt][r] = 0.f; sxy[rt][r] = 0.f; }

    // ---- main loop: 8 j-tiles of 16 columns ----
    for (int jt = 0; jt < 8; ++jt) {
        const int n  = jt * 16 + l15;       // C col = lane&15 (verified layout)
        const int rb = off(n) + qh * 4;     // b128-aligned frag dwords
        FragU bh, bl, ch, cl;
        bh.q = *(const uint4*)&XHs[rb];
        bl.q = *(const uint4*)&XLs[rb];
        ch.q = *(const uint4*)&YHs[rb];
        cl.q = *(const uint4*)&YLs[rb];
        const float cx = csx[n];
        const float cy = csy[n];
#pragma unroll
        for (int rt = 0; rt < 4; ++rt) {
            floatx4 c = {0.f, 0.f, 0.f, 0.f};
            c = __builtin_amdgcn_mfma_f32_16x16x32_bf16(a1f[rt], bh.v, c, 0, 0, 0);
            c = __builtin_amdgcn_mfma_f32_16x16x32_bf16(a2f[rt], bl.v, c, 0, 0, 0);
#pragma unroll
            for (int r = 0; r < 4; ++r)
                sxx[rt][r] = fmaf(__builtin_amdgcn_exp2f(c[r]), cx, sxx[rt][r]);
            floatx4 d = {0.f, 0.f, 0.f, 0.f};
            d = __builtin_amdgcn_mfma_f32_16x16x32_bf16(a1f[rt], ch.v, d, 0, 0, 0);
            d = __builtin_amdgcn_mfma_f32_16x16x32_bf16(a2f[rt], cl.v, d, 0, 0, 0);
#pragma unroll
            for (int r = 0; r < 4; ++r)
                sxy[rt][r] = fmaf(__builtin_amdgcn_exp2f(d[r]), cy, sxy[rt][r]);
        }
    }

    // ---- epilogue: row-scale by 2^-g_row, then block reduction ----
    float txx = 0.f, txy = 0.f;
#pragma unroll
    for (int rt = 0; rt < 4; ++rt)
#pragma unroll
        for (int r = 0; r < 4; ++r) {
            const float rs = __builtin_amdgcn_exp2f(-srg[w * 64 + rt * 16 + quad * 4 + r]);
            txx = fmaf(sxx[rt][r], rs, txx);
            txy = fmaf(sxy[rt][r], rs, txy);
        }
    for (int o = 32; o > 0; o >>= 1) {
        txx += __shfl_down(txx, o, 64);
        txy += __shfl_down(txy, o, 64);
    }
    if (lane == 0) { red[w] = txx; red[4 + w] = txy; }
    __syncthreads();
    if (tid == 0) {
        const float wt = (t == 0 || t == 127) ? 1.f : 2.f;
        part[bid]        = wt * (red[0] + red[1] + red[2] + red[3]);
        part[1024 + bid] = wt * (red[4] + red[5] + red[6] + red[7]);
    }
}

__global__ __launch_bounds__(256) void finalize_kernel(const float* __restrict__ part,
                                                       float* __restrict__ out) {
    const int tid = threadIdx.x;
    double vxx = 0.0, vxy = 0.0;
#pragma unroll
    for (int k = 0; k < 4; ++k) {
        vxx += (double)part[tid + 256 * k];
        vxy += (double)part[1024 + tid + 256 * k];
    }
    for (int o = 32; o > 0; o >>= 1) {
        vxx += __shfl_down(vxx, o, 64);
        vxy += __shfl_down(vxy, o, 64);
    }
    __shared__ double red[8];
    const int wid = tid >> 6;
    if ((tid & 63) == 0) { red[wid] = vxx; red[4 + wid] = vxy; }
    __syncthreads();
    if (tid == 0) {
        double sxx = red[0] + red[1] + red[2] + red[3];
        double sxy = red[4] + red[5] + red[6] + red[7];
        // diagonal entries (~1.0 each) included in sxx: subtract 254*512
        double e1 = (sxx - 254.0 * 512.0) / (254.0 * 512.0 * 511.0);
        double e2 = sxy / (254.0 * 512.0 * 512.0);
        out[0] = (float)(e1 - 2.0 * e2);
    }
}

extern "C" void kernel_launch(void* const* d_in, const int* in_sizes, int n_in,
                              void* d_out, int out_size, void* d_ws, size_t ws_size,
                              hipStream_t stream) {
    (void)in_sizes; (void)n_in; (void)out_size; (void)ws_size;
    const float* x = (const float*)d_in[0];
    const float* y = (const float*)d_in[1];
    float* out = (float*)d_out;
    unsigned int* ws = (unsigned int*)d_ws;
    float* part = (float*)d_ws + PART_OFF;

    prep_kernel<<<dim3(512), dim3(256), 0, stream>>>(x, y, ws);
    gram_kernel<<<dim3(1024), dim3(256), 0, stream>>>(ws, part);
    finalize_kernel<<<dim3(1), dim3(256), 0, stream>>>(part, out);
}